// Round 2
// baseline (1283.574 us; speedup 1.0000x reference)
//
#include <hip/hip_runtime.h>

#define SDIM 1024
#define EDIM 1024
#define BDIM 2
#define HDIM 16
#define DDIM 64
#define MDIM 2048   // B*S
#define N3   3072

// ---------------------------------------------------------------------------
// Kernel 1: QKV GEMM + bias, scattered into Q/K/V laid out [B,H,S,D]
// A [2048,1024] row-major, W [1024,3072] row-major.
// 128x128 tile, BK=16, 256 threads, 8x8 micro-tile per thread.
// ---------------------------------------------------------------------------
__global__ __launch_bounds__(256) void qkv_gemm_kernel(
    const float* __restrict__ A, const float* __restrict__ W,
    const float* __restrict__ bias, float* __restrict__ Qo,
    float* __restrict__ Ko, float* __restrict__ Vo) {
  const int K = EDIM, N = N3;
  __shared__ float As[16][128 + 4];  // transposed: As[k][m]; stride 132*4=528B (16B-aligned)
  __shared__ float Bs[16][128];
  int bm = blockIdx.y * 128, bn = blockIdx.x * 128;
  int tid = threadIdx.x;
  int tx = tid & 15, ty = tid >> 4;
  float acc[8][8] = {};
  for (int k0 = 0; k0 < K; k0 += 16) {
#pragma unroll
    for (int i = 0; i < 2; ++i) {
      int f = tid + i * 256;                 // float4 id, 512 per tile
      int r = f >> 2, c = (f & 3) << 2;      // A tile 128x16
      float4 v = *reinterpret_cast<const float4*>(&A[(size_t)(bm + r) * K + k0 + c]);
      As[c + 0][r] = v.x; As[c + 1][r] = v.y; As[c + 2][r] = v.z; As[c + 3][r] = v.w;
      int rb = f >> 5, cb = (f & 31) << 2;   // B tile 16x128, coalesced
      *reinterpret_cast<float4*>(&Bs[rb][cb]) =
          *reinterpret_cast<const float4*>(&W[(size_t)(k0 + rb) * N + bn + cb]);
    }
    __syncthreads();
#pragma unroll
    for (int kk = 0; kk < 16; ++kk) {
      float4 a0 = *reinterpret_cast<const float4*>(&As[kk][ty << 3]);
      float4 a1 = *reinterpret_cast<const float4*>(&As[kk][(ty << 3) + 4]);
      float4 b0 = *reinterpret_cast<const float4*>(&Bs[kk][tx << 3]);
      float4 b1 = *reinterpret_cast<const float4*>(&Bs[kk][(tx << 3) + 4]);
      float av[8] = {a0.x, a0.y, a0.z, a0.w, a1.x, a1.y, a1.z, a1.w};
      float bv[8] = {b0.x, b0.y, b0.z, b0.w, b1.x, b1.y, b1.z, b1.w};
#pragma unroll
      for (int i = 0; i < 8; ++i)
#pragma unroll
        for (int j = 0; j < 8; ++j) acc[i][j] += av[i] * bv[j];
    }
    __syncthreads();
  }
  // epilogue: bias + scatter into [B,H,S,D]
#pragma unroll
  for (int i = 0; i < 8; ++i) {
    int m = bm + (ty << 3) + i;
    int b = m >> 10, s = m & 1023;
#pragma unroll
    for (int j = 0; j < 8; ++j) {
      int n = bn + (tx << 3) + j;
      float val = acc[i][j] + bias[n];
      int which = n >> 10;     // 0=q 1=k 2=v
      int e = n & 1023;
      int h = e >> 6, d = e & 63;
      float* dst = (which == 0) ? Qo : (which == 1) ? Ko : Vo;
      dst[((((size_t)(b * HDIM + h)) << 10) + s) * DDIM + d] = val;
    }
  }
}

// ---------------------------------------------------------------------------
// Kernel 2: scores (scaled, causal-masked) + softmax, fused; writes weights
// once. One block = one (b,h) and 8 q-rows; scores tile lives in LDS.
// ---------------------------------------------------------------------------
__global__ __launch_bounds__(256) void attn_softmax_kernel(
    const float* __restrict__ Q, const float* __restrict__ Kmat,
    float* __restrict__ Wout) {
  __shared__ float qs[8][64];
  __shared__ float sc[8][1024];
  int bh = blockIdx.y;            // 0..31
  int q0 = blockIdx.x * 8;
  int tid = threadIdx.x;
  const float* Qb = Q + (((size_t)bh) << 10) * DDIM;
  const float* Kb = Kmat + (((size_t)bh) << 10) * DDIM;
  for (int i = tid; i < 8 * 64; i += 256)
    qs[i >> 6][i & 63] = Qb[(size_t)(q0 + (i >> 6)) * DDIM + (i & 63)];
  __syncthreads();

  float acc[4][8];
#pragma unroll
  for (int kb = 0; kb < 4; ++kb)
#pragma unroll
    for (int qi = 0; qi < 8; ++qi) acc[kb][qi] = 0.f;

#pragma unroll
  for (int d4 = 0; d4 < 16; ++d4) {
    float4 q4[8];
#pragma unroll
    for (int qi = 0; qi < 8; ++qi)
      q4[qi] = *reinterpret_cast<const float4*>(&qs[qi][d4 << 2]);
#pragma unroll
    for (int kb = 0; kb < 4; ++kb) {
      int kk = kb * 256 + tid;
      float4 k4 = *reinterpret_cast<const float4*>(&Kb[(size_t)kk * DDIM + (d4 << 2)]);
#pragma unroll
      for (int qi = 0; qi < 8; ++qi)
        acc[kb][qi] += q4[qi].x * k4.x + q4[qi].y * k4.y +
                       q4[qi].z * k4.z + q4[qi].w * k4.w;
    }
  }
  const float scale = 0.125f;   // 1/sqrt(64)
#pragma unroll
  for (int kb = 0; kb < 4; ++kb) {
    int kk = kb * 256 + tid;
#pragma unroll
    for (int qi = 0; qi < 8; ++qi) {
      int qg = q0 + qi;
      sc[qi][kk] = (kk <= qg) ? acc[kb][qi] * scale : -10000.0f;
    }
  }
  __syncthreads();

  // per-row softmax: 32 threads per row
  int g = tid >> 5, l = tid & 31;
  float m = -3.4e38f;
  for (int k = l; k < 1024; k += 32) m = fmaxf(m, sc[g][k]);
#pragma unroll
  for (int off = 16; off; off >>= 1) m = fmaxf(m, __shfl_xor(m, off, 32));
  float s = 0.f;
  for (int k = l; k < 1024; k += 32) {
    float e = __expf(sc[g][k] - m);
    sc[g][k] = e;
    s += e;
  }
#pragma unroll
  for (int off = 16; off; off >>= 1) s += __shfl_xor(s, off, 32);
  float inv = 1.0f / s;
  float* Wr = Wout + ((((size_t)bh << 10) + q0 + g) << 10);
  for (int k = l; k < 1024; k += 32) Wr[k] = sc[g][k] * inv;
}

// ---------------------------------------------------------------------------
// Kernel 3: PV GEMM per (b,h): O[1024x64] = W[1024x1024] @ V[1024x64],
// fused head-merge into ctx [B,S,E]. 64x64 tile, 4x4 micro.
// ---------------------------------------------------------------------------
__global__ __launch_bounds__(256) void pv_kernel(
    const float* __restrict__ Wts, const float* __restrict__ V,
    float* __restrict__ ctx) {
  __shared__ float Ws[16][64 + 4];   // transposed [k][m]; stride 68*4=272B (16B-aligned)
  __shared__ float Vs[16][64];
  int bh = blockIdx.y, bm = blockIdx.x * 64;
  int b = bh >> 4, h = bh & 15;
  const float* Wb = Wts + (((size_t)bh) << 20);
  const float* Vb = V + (((size_t)bh) << 10) * DDIM;
  int tid = threadIdx.x, tx = tid & 15, ty = tid >> 4;
  float acc[4][4] = {};
  for (int k0 = 0; k0 < 1024; k0 += 16) {
    {
      int r = tid >> 2, c = (tid & 3) << 2;   // W tile 64x16
      float4 v = *reinterpret_cast<const float4*>(&Wb[(size_t)(bm + r) * 1024 + k0 + c]);
      Ws[c + 0][r] = v.x; Ws[c + 1][r] = v.y; Ws[c + 2][r] = v.z; Ws[c + 3][r] = v.w;
      int rv = tid >> 4, cv = (tid & 15) << 2;  // V tile 16x64
      *reinterpret_cast<float4*>(&Vs[rv][cv]) =
          *reinterpret_cast<const float4*>(&Vb[(size_t)(k0 + rv) * DDIM + cv]);
    }
    __syncthreads();
#pragma unroll
    for (int kk = 0; kk < 16; ++kk) {
      float4 a = *reinterpret_cast<const float4*>(&Ws[kk][ty << 2]);
      float4 bv = *reinterpret_cast<const float4*>(&Vs[kk][tx << 2]);
      float av[4] = {a.x, a.y, a.z, a.w};
      float bb[4] = {bv.x, bv.y, bv.z, bv.w};
#pragma unroll
      for (int i = 0; i < 4; ++i)
#pragma unroll
        for (int j = 0; j < 4; ++j) acc[i][j] += av[i] * bb[j];
    }
    __syncthreads();
  }
#pragma unroll
  for (int i = 0; i < 4; ++i) {
    int m = bm + (ty << 2) + i;   // s index
    float4 o = {acc[i][0], acc[i][1], acc[i][2], acc[i][3]};
    *reinterpret_cast<float4*>(
        &ctx[(size_t)(b * SDIM + m) * EDIM + h * DDIM + (tx << 2)]) = o;
  }
}

// ---------------------------------------------------------------------------
// Kernel 4: proj GEMM + bias: out[2048,1024] = ctx @ W_proj + b_proj
// 64x128 tile, BK=16, 4x8 micro.
// ---------------------------------------------------------------------------
__global__ __launch_bounds__(256) void proj_gemm_kernel(
    const float* __restrict__ Ctx, const float* __restrict__ Wp,
    const float* __restrict__ bias, float* __restrict__ Out) {
  __shared__ float As[16][64 + 4];
  __shared__ float Bs[16][128];
  int bm = blockIdx.y * 64, bn = blockIdx.x * 128;
  int tid = threadIdx.x, tx = tid & 15, ty = tid >> 4;
  float acc[4][8] = {};
  for (int k0 = 0; k0 < 1024; k0 += 16) {
    {
      int r = tid >> 2, c = (tid & 3) << 2;   // A tile 64x16
      float4 v = *reinterpret_cast<const float4*>(&Ctx[(size_t)(bm + r) * 1024 + k0 + c]);
      As[c + 0][r] = v.x; As[c + 1][r] = v.y; As[c + 2][r] = v.z; As[c + 3][r] = v.w;
#pragma unroll
      for (int i = 0; i < 2; ++i) {
        int f = tid + i * 256;
        int rb = f >> 5, cb = (f & 31) << 2;  // B tile 16x128
        *reinterpret_cast<float4*>(&Bs[rb][cb]) =
            *reinterpret_cast<const float4*>(&Wp[(size_t)(k0 + rb) * 1024 + bn + cb]);
      }
    }
    __syncthreads();
#pragma unroll
    for (int kk = 0; kk < 16; ++kk) {
      float4 a = *reinterpret_cast<const float4*>(&As[kk][ty << 2]);
      float4 b0 = *reinterpret_cast<const float4*>(&Bs[kk][tx << 3]);
      float4 b1 = *reinterpret_cast<const float4*>(&Bs[kk][(tx << 3) + 4]);
      float av[4] = {a.x, a.y, a.z, a.w};
      float bv[8] = {b0.x, b0.y, b0.z, b0.w, b1.x, b1.y, b1.z, b1.w};
#pragma unroll
      for (int i = 0; i < 4; ++i)
#pragma unroll
        for (int j = 0; j < 8; ++j) acc[i][j] += av[i] * bv[j];
    }
    __syncthreads();
  }
#pragma unroll
  for (int i = 0; i < 4; ++i) {
    int m = bm + (ty << 2) + i;
#pragma unroll
    for (int j = 0; j < 8; ++j) {
      int n = bn + (tx << 3) + j;
      Out[(size_t)m * 1024 + n] = acc[i][j] + bias[n];
    }
  }
}

extern "C" void kernel_launch(void* const* d_in, const int* in_sizes, int n_in,
                              void* d_out, int out_size, void* d_ws, size_t ws_size,
                              hipStream_t stream) {
  const float* hs     = (const float*)d_in[0];
  const float* W_attn = (const float*)d_in[1];
  const float* b_attn = (const float*)d_in[2];
  const float* W_proj = (const float*)d_in[3];
  const float* b_proj = (const float*)d_in[4];

  float* out_attn = (float*)d_out;                          // [2,1024,1024]
  float* out_w    = (float*)d_out + (size_t)MDIM * EDIM;    // [2,16,1024,1024]

  // workspace layout: Q,K,V [B,H,S,D] (3 x 8 MiB) + ctx [B,S,E] (8 MiB) = 32 MiB
  const size_t QSZ = (size_t)BDIM * HDIM * SDIM * DDIM;     // 2 Mi floats
  float* Q   = (float*)d_ws;
  float* Km  = Q + QSZ;
  float* V   = Km + QSZ;
  float* ctx = V + QSZ;                                     // 2 Mi floats

  qkv_gemm_kernel<<<dim3(N3 / 128, MDIM / 128), 256, 0, stream>>>(
      hs, W_attn, b_attn, Q, Km, V);
  attn_softmax_kernel<<<dim3(SDIM / 8, BDIM * HDIM), 256, 0, stream>>>(
      Q, Km, out_w);
  pv_kernel<<<dim3(SDIM / 64, BDIM * HDIM), 256, 0, stream>>>(
      out_w, V, ctx);
  proj_gemm_kernel<<<dim3(EDIM / 128, MDIM / 64), 256, 0, stream>>>(
      ctx, W_proj, b_proj, out_attn);
}

// Round 7
// 1010.499 us; speedup vs baseline: 1.2702x; 1.2702x over previous
//
#include <hip/hip_runtime.h>

#define SDIM 1024
#define EDIM 1024
#define BDIM 2
#define HDIM 16
#define DDIM 64
#define MDIM 2048   // B*S
#define N3   3072

typedef __attribute__((ext_vector_type(8))) short bf16x8;
typedef __attribute__((ext_vector_type(4))) float f32x4;

__device__ __forceinline__ ushort f2bf(float f) {
  union { float f; unsigned u; } x; x.f = f;
  unsigned u = x.u;
  u += 0x7FFFu + ((u >> 16) & 1u);   // round-to-nearest-even
  return (ushort)(u >> 16);
}

// ---------------------------------------------------------------------------
// Cast hidden_states fp32 -> bf16 (row-major [2048][1024])
// ---------------------------------------------------------------------------
__global__ __launch_bounds__(256) void cast_bf16_kernel(
    const float* __restrict__ in, ushort* __restrict__ out, int n) {
  int i = (blockIdx.x * 256 + threadIdx.x) * 4;
  if (i < n) {
    float4 v = *reinterpret_cast<const float4*>(&in[i]);
    ushort4 o;
    o.x = f2bf(v.x); o.y = f2bf(v.y); o.z = f2bf(v.z); o.w = f2bf(v.w);
    *reinterpret_cast<ushort4*>(&out[i]) = o;
  }
}

// ---------------------------------------------------------------------------
// Transpose-cast W_attn fp32 [1024][3072] -> WT bf16 [3072][1024]
// ---------------------------------------------------------------------------
__global__ __launch_bounds__(256) void transpose_cast_kernel(
    const float* __restrict__ W, ushort* __restrict__ WT) {
  __shared__ float t[32][33];
  int n0 = blockIdx.x * 32, k0 = blockIdx.y * 32;
  int tx = threadIdx.x & 31, ty = threadIdx.x >> 5;   // 32 x 8
#pragma unroll
  for (int j = 0; j < 4; ++j)
    t[ty + j * 8][tx] = W[(size_t)(k0 + ty + j * 8) * N3 + n0 + tx];
  __syncthreads();
#pragma unroll
  for (int j = 0; j < 4; ++j)
    WT[(size_t)(n0 + ty + j * 8) * EDIM + k0 + tx] = f2bf(t[tx][ty + j * 8]);
}

// ---------------------------------------------------------------------------
// Kernel 1 (MFMA): QKV GEMM + bias, scatter into Q/K/V [B,H,S,D].
// C[m][n] = sum_k Abf[m][k] * WT[n][k]  (B^T-input pattern).
// 128x128 tile, BK=32, 4 waves (2x2), each wave 64x64 = 4x4 frags of
// mfma_f32_16x16x32_bf16. Layouts per guide §3 (m89/m91 verified):
//   A-frag: lane l holds A[l&15][(l>>4)*8 + j], j=0..7 (16B ds_read)
//   B-frag: lane l holds Bcol[l&15][(l>>4)*8 + j] = WT row slice
//   C/D  : col = lane&15, row = (lane>>4)*4 + reg
// ---------------------------------------------------------------------------
__global__ __launch_bounds__(256) void qkv_gemm_mfma(
    const ushort* __restrict__ Abf, const ushort* __restrict__ WT,
    const float* __restrict__ bias, float* __restrict__ Qo,
    float* __restrict__ Ko, float* __restrict__ Vo) {
  const int K = EDIM;
  __shared__ ushort As[128][40];   // 32 k + 8 pad; row stride 80B (16B-aligned)
  __shared__ ushort Bs[128][40];
  int bm = blockIdx.y * 128, bn = blockIdx.x * 128;
  int tid = threadIdx.x;
  int lane = tid & 63, wave = tid >> 6;
  int wr = (wave >> 1) * 64, wc = (wave & 1) * 64;
  int fr = lane & 15;           // row/col within fragment
  int ko = (lane >> 4) * 8;     // k-offset within BK=32

  f32x4 acc[4][4] = {};

  for (int k0 = 0; k0 < K; k0 += 32) {
#pragma unroll
    for (int i = 0; i < 2; ++i) {
      int c = tid + i * 256;            // 16B-chunk id, 512 per tile
      int r = c >> 2, o = (c & 3) * 8;  // row, bf16 offset
      *reinterpret_cast<float4*>(&As[r][o]) =
          *reinterpret_cast<const float4*>(&Abf[(size_t)(bm + r) * K + k0 + o]);
      *reinterpret_cast<float4*>(&Bs[r][o]) =
          *reinterpret_cast<const float4*>(&WT[(size_t)(bn + r) * K + k0 + o]);
    }
    __syncthreads();
    bf16x8 a[4], b[4];
#pragma unroll
    for (int f = 0; f < 4; ++f) {
      a[f] = *reinterpret_cast<const bf16x8*>(&As[wr + f * 16 + fr][ko]);
      b[f] = *reinterpret_cast<const bf16x8*>(&Bs[wc + f * 16 + fr][ko]);
    }
#pragma unroll
    for (int i = 0; i < 4; ++i)
#pragma unroll
      for (int j = 0; j < 4; ++j)
        acc[i][j] = __builtin_amdgcn_mfma_f32_16x16x32_bf16(a[i], b[j],
                                                            acc[i][j], 0, 0, 0);
    __syncthreads();
  }

  // epilogue: bias + scatter into [B,H,S,D]
  int rbase = (lane >> 4) << 2;
#pragma unroll
  for (int i = 0; i < 4; ++i)
#pragma unroll
    for (int j = 0; j < 4; ++j)
#pragma unroll
      for (int r = 0; r < 4; ++r) {
        int m = bm + wr + i * 16 + rbase + r;
        int n = bn + wc + j * 16 + (lane & 15);
        float val = acc[i][j][r] + bias[n];
        int b = m >> 10, s = m & 1023;
        int which = n >> 10;     // 0=q 1=k 2=v
        int e = n & 1023;
        int h = e >> 6, d = e & 63;
        float* dst = (which == 0) ? Qo : (which == 1) ? Ko : Vo;
        dst[((((size_t)(b * HDIM + h)) << 10) + s) * DDIM + d] = val;
      }
}

// ---------------------------------------------------------------------------
// Kernel 2: scores + causal mask + softmax, all register-resident (fp32).
// ---------------------------------------------------------------------------
__global__ __launch_bounds__(256) void attn_softmax_kernel(
    const float* __restrict__ Q, const float* __restrict__ Kmat,
    float* __restrict__ Wout) {
  __shared__ float qs[8][64];
  __shared__ float redA[8][4];
  __shared__ float redB[8][4];
  int bh = blockIdx.y;            // 0..31
  int q0 = blockIdx.x * 8;
  int tid = threadIdx.x;
  int lane = tid & 63, wid = tid >> 6;
  const float* Qb = Q + (((size_t)bh) << 10) * DDIM;
  const float* Kb = Kmat + (((size_t)bh) << 10) * DDIM;
  if (tid < 128) {
    int r = tid >> 4, c = (tid & 15) << 2;
    *reinterpret_cast<float4*>(&qs[r][c]) =
        *reinterpret_cast<const float4*>(&Qb[(size_t)(q0 + r) * DDIM + c]);
  }
  __syncthreads();

  float sc[4][8];
#pragma unroll
  for (int kb = 0; kb < 4; ++kb)
#pragma unroll
    for (int qi = 0; qi < 8; ++qi) sc[kb][qi] = 0.f;

  const float* kp0 = &Kb[(size_t)(tid) * DDIM];
  const float* kp1 = &Kb[(size_t)(256 + tid) * DDIM];
  const float* kp2 = &Kb[(size_t)(512 + tid) * DDIM];
  const float* kp3 = &Kb[(size_t)(768 + tid) * DDIM];

#pragma unroll
  for (int d4 = 0; d4 < 16; ++d4) {
    float4 k0 = *reinterpret_cast<const float4*>(kp0 + (d4 << 2));
    float4 k1 = *reinterpret_cast<const float4*>(kp1 + (d4 << 2));
    float4 k2 = *reinterpret_cast<const float4*>(kp2 + (d4 << 2));
    float4 k3 = *reinterpret_cast<const float4*>(kp3 + (d4 << 2));
#pragma unroll
    for (int qi = 0; qi < 8; ++qi) {
      float4 q4 = *reinterpret_cast<const float4*>(&qs[qi][d4 << 2]);
      sc[0][qi] += q4.x * k0.x + q4.y * k0.y + q4.z * k0.z + q4.w * k0.w;
      sc[1][qi] += q4.x * k1.x + q4.y * k1.y + q4.z * k1.z + q4.w * k1.w;
      sc[2][qi] += q4.x * k2.x + q4.y * k2.y + q4.z * k2.z + q4.w * k2.w;
      sc[3][qi] += q4.x * k3.x + q4.y * k3.y + q4.z * k3.z + q4.w * k3.w;
    }
  }

  const float scale = 0.125f;   // 1/sqrt(64)
  float rmax[8];
#pragma unroll
  for (int qi = 0; qi < 8; ++qi) {
    int qg = q0 + qi;
    float m = -3.4e38f;
#pragma unroll
    for (int kb = 0; kb < 4; ++kb) {
      float s = sc[kb][qi] * scale;
      sc[kb][qi] = s;
      int kk = kb * 256 + tid;
      if (kk <= qg) m = fmaxf(m, s);
    }
#pragma unroll
    for (int off = 32; off; off >>= 1) m = fmaxf(m, __shfl_xor(m, off));
    if (lane == 0) redA[qi][wid] = m;
  }
  __syncthreads();
#pragma unroll
  for (int qi = 0; qi < 8; ++qi)
    rmax[qi] = fmaxf(fmaxf(redA[qi][0], redA[qi][1]),
                     fmaxf(redA[qi][2], redA[qi][3]));
#pragma unroll
  for (int qi = 0; qi < 8; ++qi) {
    int qg = q0 + qi;
    float s = 0.f;
#pragma unroll
    for (int kb = 0; kb < 4; ++kb) {
      int kk = kb * 256 + tid;
      float e = (kk <= qg) ? __expf(sc[kb][qi] - rmax[qi]) : 0.f;
      sc[kb][qi] = e;
      s += e;
    }
#pragma unroll
    for (int off = 32; off; off >>= 1) s += __shfl_xor(s, off);
    if (lane == 0) redB[qi][wid] = s;
  }
  __syncthreads();
#pragma unroll
  for (int qi = 0; qi < 8; ++qi) {
    float inv = 1.0f / (redB[qi][0] + redB[qi][1] + redB[qi][2] + redB[qi][3]);
    float* Wr = Wout + ((((size_t)bh << 10) + q0 + qi) << 10);
#pragma unroll
    for (int kb = 0; kb < 4; ++kb)
      Wr[kb * 256 + tid] = sc[kb][qi] * inv;
  }
}

// ---------------------------------------------------------------------------
// Kernel 3: PV GEMM per (b,h) (fp32, unchanged/validated)
// ---------------------------------------------------------------------------
__global__ __launch_bounds__(256) void pv_kernel(
    const float* __restrict__ Wts, const float* __restrict__ V,
    float* __restrict__ ctx) {
  __shared__ float Ws[16][64 + 4];
  __shared__ float Vs[16][64];
  int bh = blockIdx.y, bm = blockIdx.x * 64;
  int b = bh >> 4, h = bh & 15;
  const float* Wb = Wts + (((size_t)bh) << 20);
  const float* Vb = V + (((size_t)bh) << 10) * DDIM;
  int tid = threadIdx.x, tx = tid & 15, ty = tid >> 4;
  float acc[4][4] = {};
  for (int k0 = 0; k0 < 1024; k0 += 16) {
    {
      int r = tid >> 2, c = (tid & 3) << 2;
      float4 v = *reinterpret_cast<const float4*>(&Wb[(size_t)(bm + r) * 1024 + k0 + c]);
      Ws[c + 0][r] = v.x; Ws[c + 1][r] = v.y; Ws[c + 2][r] = v.z; Ws[c + 3][r] = v.w;
      int rv = tid >> 4, cv = (tid & 15) << 2;
      *reinterpret_cast<float4*>(&Vs[rv][cv]) =
          *reinterpret_cast<const float4*>(&Vb[(size_t)(k0 + rv) * DDIM + cv]);
    }
    __syncthreads();
#pragma unroll
    for (int kk = 0; kk < 16; ++kk) {
      float4 a = *reinterpret_cast<const float4*>(&Ws[kk][ty << 2]);
      float4 bv = *reinterpret_cast<const float4*>(&Vs[kk][tx << 2]);
      float av[4] = {a.x, a.y, a.z, a.w};
      float bb[4] = {bv.x, bv.y, bv.z, bv.w};
#pragma unroll
      for (int i = 0; i < 4; ++i)
#pragma unroll
        for (int j = 0; j < 4; ++j) acc[i][j] += av[i] * bb[j];
    }
    __syncthreads();
  }
#pragma unroll
  for (int i = 0; i < 4; ++i) {
    int m = bm + (ty << 2) + i;
    float4 o = {acc[i][0], acc[i][1], acc[i][2], acc[i][3]};
    *reinterpret_cast<float4*>(
        &ctx[(size_t)(b * SDIM + m) * EDIM + h * DDIM + (tx << 2)]) = o;
  }
}

// ---------------------------------------------------------------------------
// Kernel 4: proj GEMM + bias (fp32, unchanged/validated)
// ---------------------------------------------------------------------------
__global__ __launch_bounds__(256) void proj_gemm_kernel(
    const float* __restrict__ Ctx, const float* __restrict__ Wp,
    const float* __restrict__ bias, float* __restrict__ Out) {
  __shared__ float As[16][64 + 4];
  __shared__ float Bs[16][128];
  int bm = blockIdx.y * 64, bn = blockIdx.x * 128;
  int tid = threadIdx.x, tx = tid & 15, ty = tid >> 4;
  float acc[4][8] = {};
  for (int k0 = 0; k0 < 1024; k0 += 16) {
    {
      int r = tid >> 2, c = (tid & 3) << 2;
      float4 v = *reinterpret_cast<const float4*>(&Ctx[(size_t)(bm + r) * 1024 + k0 + c]);
      As[c + 0][r] = v.x; As[c + 1][r] = v.y; As[c + 2][r] = v.z; As[c + 3][r] = v.w;
#pragma unroll
      for (int i = 0; i < 2; ++i) {
        int f = tid + i * 256;
        int rb = f >> 5, cb = (f & 31) << 2;
        *reinterpret_cast<float4*>(&Bs[rb][cb]) =
            *reinterpret_cast<const float4*>(&Wp[(size_t)(k0 + rb) * 1024 + bn + cb]);
      }
    }
    __syncthreads();
#pragma unroll
    for (int kk = 0; kk < 16; ++kk) {
      float4 a = *reinterpret_cast<const float4*>(&As[kk][ty << 2]);
      float4 b0 = *reinterpret_cast<const float4*>(&Bs[kk][tx << 3]);
      float4 b1 = *reinterpret_cast<const float4*>(&Bs[kk][(tx << 3) + 4]);
      float av[4] = {a.x, a.y, a.z, a.w};
      float bv[8] = {b0.x, b0.y, b0.z, b0.w, b1.x, b1.y, b1.z, b1.w};
#pragma unroll
      for (int i = 0; i < 4; ++i)
#pragma unroll
        for (int j = 0; j < 8; ++j) acc[i][j] += av[i] * bv[j];
    }
    __syncthreads();
  }
#pragma unroll
  for (int i = 0; i < 4; ++i) {
    int m = bm + (ty << 2) + i;
#pragma unroll
    for (int j = 0; j < 8; ++j) {
      int n = bn + (tx << 3) + j;
      Out[(size_t)m * 1024 + n] = acc[i][j] + bias[n];
    }
  }
}

extern "C" void kernel_launch(void* const* d_in, const int* in_sizes, int n_in,
                              void* d_out, int out_size, void* d_ws, size_t ws_size,
                              hipStream_t stream) {
  const float* hs     = (const float*)d_in[0];
  const float* W_attn = (const float*)d_in[1];
  const float* b_attn = (const float*)d_in[2];
  const float* W_proj = (const float*)d_in[3];
  const float* b_proj = (const float*)d_in[4];

  float* out_attn = (float*)d_out;                          // [2,1024,1024]
  float* out_w    = (float*)d_out + (size_t)MDIM * EDIM;    // [2,16,1024,1024]

  // ws layout: Q,K,V [B,H,S,D] fp32 (24 MiB) + ctx (8 MiB) + Abf bf16 (4 MiB)
  //            + WT bf16 (6 MiB)  = 42 MiB
  const size_t QSZ = (size_t)BDIM * HDIM * SDIM * DDIM;     // 2 Mi floats
  float* Q   = (float*)d_ws;
  float* Km  = Q + QSZ;
  float* V   = Km + QSZ;
  float* ctx = V + QSZ;
  ushort* Abf = (ushort*)(ctx + (size_t)MDIM * EDIM);
  ushort* WT  = Abf + (size_t)MDIM * EDIM;

  cast_bf16_kernel<<<2048, 256, 0, stream>>>(hs, Abf, MDIM * EDIM);
  transpose_cast_kernel<<<dim3(N3 / 32, EDIM / 32), 256, 0, stream>>>(W_attn, WT);
  qkv_gemm_mfma<<<dim3(N3 / 128, MDIM / 128), 256, 0, stream>>>(
      Abf, WT, b_attn, Q, Km, V);
  attn_softmax_kernel<<<dim3(SDIM / 8, BDIM * HDIM), 256, 0, stream>>>(
      Q, Km, out_w);
  pv_kernel<<<dim3(SDIM / 64, BDIM * HDIM), 256, 0, stream>>>(
      out_w, V, ctx);
  proj_gemm_kernel<<<dim3(EDIM / 128, MDIM / 64), 256, 0, stream>>>(
      ctx, W_proj, b_proj, out_attn);
}

// Round 10
// 534.536 us; speedup vs baseline: 2.4013x; 1.8904x over previous
//
#include <hip/hip_runtime.h>

#define SDIM 1024
#define EDIM 1024
#define BDIM 2
#define HDIM 16
#define DDIM 64
#define MDIM 2048   // B*S
#define N3   3072

typedef __attribute__((ext_vector_type(8))) short bf16x8;
typedef __attribute__((ext_vector_type(4))) float f32x4;

__device__ __forceinline__ ushort f2bf(float f) {
  union { float f; unsigned u; } x; x.f = f;
  unsigned u = x.u;
  u += 0x7FFFu + ((u >> 16) & 1u);   // round-to-nearest-even
  return (ushort)(u >> 16);
}

// ---------------------------------------------------------------------------
// Cast hidden_states fp32 -> bf16 (row-major [2048][1024])
// ---------------------------------------------------------------------------
__global__ __launch_bounds__(256) void cast_bf16_kernel(
    const float* __restrict__ in, ushort* __restrict__ out, int n) {
  int i = (blockIdx.x * 256 + threadIdx.x) * 4;
  if (i < n) {
    float4 v = *reinterpret_cast<const float4*>(&in[i]);
    ushort4 o;
    o.x = f2bf(v.x); o.y = f2bf(v.y); o.z = f2bf(v.z); o.w = f2bf(v.w);
    *reinterpret_cast<ushort4*>(&out[i]) = o;
  }
}

// ---------------------------------------------------------------------------
// Transpose-cast W fp32 [EDIM][ncols] -> WT bf16 [ncols][EDIM]
// (used for W_attn ncols=3072 and W_proj ncols=1024)
// ---------------------------------------------------------------------------
__global__ __launch_bounds__(256) void transpose_cast_kernel(
    const float* __restrict__ W, ushort* __restrict__ WT, int ncols) {
  __shared__ float t[32][33];
  int n0 = blockIdx.x * 32, k0 = blockIdx.y * 32;
  int tx = threadIdx.x & 31, ty = threadIdx.x >> 5;   // 32 x 8
#pragma unroll
  for (int j = 0; j < 4; ++j)
    t[ty + j * 8][tx] = W[(size_t)(k0 + ty + j * 8) * ncols + n0 + tx];
  __syncthreads();
#pragma unroll
  for (int j = 0; j < 4; ++j)
    WT[(size_t)(n0 + ty + j * 8) * EDIM + k0 + tx] = f2bf(t[tx][ty + j * 8]);
}

// ---------------------------------------------------------------------------
// Kernel 1 (MFMA): QKV GEMM + bias, scatter into Q/K/V [B,H,S,D].
// (validated Round 7 — unchanged)
// ---------------------------------------------------------------------------
__global__ __launch_bounds__(256) void qkv_gemm_mfma(
    const ushort* __restrict__ Abf, const ushort* __restrict__ WT,
    const float* __restrict__ bias, float* __restrict__ Qo,
    float* __restrict__ Ko, float* __restrict__ Vo) {
  const int K = EDIM;
  __shared__ ushort As[128][40];   // 32 k + 8 pad; row stride 80B (16B-aligned)
  __shared__ ushort Bs[128][40];
  int bm = blockIdx.y * 128, bn = blockIdx.x * 128;
  int tid = threadIdx.x;
  int lane = tid & 63, wave = tid >> 6;
  int wr = (wave >> 1) * 64, wc = (wave & 1) * 64;
  int fr = lane & 15;           // row/col within fragment
  int ko = (lane >> 4) * 8;     // k-offset within BK=32

  f32x4 acc[4][4] = {};

  for (int k0 = 0; k0 < K; k0 += 32) {
#pragma unroll
    for (int i = 0; i < 2; ++i) {
      int c = tid + i * 256;            // 16B-chunk id, 512 per tile
      int r = c >> 2, o = (c & 3) * 8;  // row, bf16 offset
      *reinterpret_cast<float4*>(&As[r][o]) =
          *reinterpret_cast<const float4*>(&Abf[(size_t)(bm + r) * K + k0 + o]);
      *reinterpret_cast<float4*>(&Bs[r][o]) =
          *reinterpret_cast<const float4*>(&WT[(size_t)(bn + r) * K + k0 + o]);
    }
    __syncthreads();
    bf16x8 a[4], b[4];
#pragma unroll
    for (int f = 0; f < 4; ++f) {
      a[f] = *reinterpret_cast<const bf16x8*>(&As[wr + f * 16 + fr][ko]);
      b[f] = *reinterpret_cast<const bf16x8*>(&Bs[wc + f * 16 + fr][ko]);
    }
#pragma unroll
    for (int i = 0; i < 4; ++i)
#pragma unroll
      for (int j = 0; j < 4; ++j)
        acc[i][j] = __builtin_amdgcn_mfma_f32_16x16x32_bf16(a[i], b[j],
                                                            acc[i][j], 0, 0, 0);
    __syncthreads();
  }

  // epilogue: bias + scatter into [B,H,S,D]
  int rbase = (lane >> 4) << 2;
#pragma unroll
  for (int i = 0; i < 4; ++i)
#pragma unroll
    for (int j = 0; j < 4; ++j)
#pragma unroll
      for (int r = 0; r < 4; ++r) {
        int m = bm + wr + i * 16 + rbase + r;
        int n = bn + wc + j * 16 + (lane & 15);
        float val = acc[i][j][r] + bias[n];
        int b = m >> 10, s = m & 1023;
        int which = n >> 10;     // 0=q 1=k 2=v
        int e = n & 1023;
        int h = e >> 6, d = e & 63;
        float* dst = (which == 0) ? Qo : (which == 1) ? Ko : Vo;
        dst[((((size_t)(b * HDIM + h)) << 10) + s) * DDIM + d] = val;
      }
}

// ---------------------------------------------------------------------------
// Kernel 2: scores + causal mask + softmax, register-resident.
// FIX vs R7: dynamic d4 loop (#pragma unroll 1) + 1-deep manual K prefetch.
// R7's fully-unrolled loop hoisted 16x4 float4 loads = 256 VGPRs -> spill.
// Live set now bounded: sc 32 + K cur/next 32 + q 4 + addr ~ 100 VGPRs.
// ---------------------------------------------------------------------------
__global__ __launch_bounds__(256) void attn_softmax_kernel(
    const float* __restrict__ Q, const float* __restrict__ Kmat,
    float* __restrict__ Wout) {
  __shared__ float qs[8][64];
  __shared__ float redA[8][4];
  __shared__ float redB[8][4];
  int bh = blockIdx.y;            // 0..31
  int q0 = blockIdx.x * 8;
  int tid = threadIdx.x;
  int lane = tid & 63, wid = tid >> 6;
  const float* Qb = Q + (((size_t)bh) << 10) * DDIM;
  const float* Kb = Kmat + (((size_t)bh) << 10) * DDIM;
  if (tid < 128) {
    int r = tid >> 4, c = (tid & 15) << 2;
    *reinterpret_cast<float4*>(&qs[r][c]) =
        *reinterpret_cast<const float4*>(&Qb[(size_t)(q0 + r) * DDIM + c]);
  }
  __syncthreads();

  float sc[4][8];
#pragma unroll
  for (int kb = 0; kb < 4; ++kb)
#pragma unroll
    for (int qi = 0; qi < 8; ++qi) sc[kb][qi] = 0.f;

  const float* kp0 = &Kb[(size_t)(tid) * DDIM];
  const float* kp1 = &Kb[(size_t)(256 + tid) * DDIM];
  const float* kp2 = &Kb[(size_t)(512 + tid) * DDIM];
  const float* kp3 = &Kb[(size_t)(768 + tid) * DDIM];

  float4 kc0 = *reinterpret_cast<const float4*>(kp0);
  float4 kc1 = *reinterpret_cast<const float4*>(kp1);
  float4 kc2 = *reinterpret_cast<const float4*>(kp2);
  float4 kc3 = *reinterpret_cast<const float4*>(kp3);

#pragma unroll 1
  for (int d4 = 0; d4 < 16; ++d4) {
    int nx = ((d4 + 1) & 15) << 2;   // wraps on last iter: harmless L1 re-read
    float4 kn0 = *reinterpret_cast<const float4*>(kp0 + nx);
    float4 kn1 = *reinterpret_cast<const float4*>(kp1 + nx);
    float4 kn2 = *reinterpret_cast<const float4*>(kp2 + nx);
    float4 kn3 = *reinterpret_cast<const float4*>(kp3 + nx);
#pragma unroll
    for (int qi = 0; qi < 8; ++qi) {
      float4 q4 = *reinterpret_cast<const float4*>(&qs[qi][d4 << 2]);
      sc[0][qi] += q4.x * kc0.x + q4.y * kc0.y + q4.z * kc0.z + q4.w * kc0.w;
      sc[1][qi] += q4.x * kc1.x + q4.y * kc1.y + q4.z * kc1.z + q4.w * kc1.w;
      sc[2][qi] += q4.x * kc2.x + q4.y * kc2.y + q4.z * kc2.z + q4.w * kc2.w;
      sc[3][qi] += q4.x * kc3.x + q4.y * kc3.y + q4.z * kc3.z + q4.w * kc3.w;
    }
    kc0 = kn0; kc1 = kn1; kc2 = kn2; kc3 = kn3;
  }

  const float scale = 0.125f;   // 1/sqrt(64)
  float rmax[8];
#pragma unroll
  for (int qi = 0; qi < 8; ++qi) {
    int qg = q0 + qi;
    float m = -3.4e38f;
#pragma unroll
    for (int kb = 0; kb < 4; ++kb) {
      float s = sc[kb][qi] * scale;
      sc[kb][qi] = s;
      int kk = kb * 256 + tid;
      if (kk <= qg) m = fmaxf(m, s);
    }
#pragma unroll
    for (int off = 32; off; off >>= 1) m = fmaxf(m, __shfl_xor(m, off));
    if (lane == 0) redA[qi][wid] = m;
  }
  __syncthreads();
#pragma unroll
  for (int qi = 0; qi < 8; ++qi)
    rmax[qi] = fmaxf(fmaxf(redA[qi][0], redA[qi][1]),
                     fmaxf(redA[qi][2], redA[qi][3]));
#pragma unroll
  for (int qi = 0; qi < 8; ++qi) {
    int qg = q0 + qi;
    float s = 0.f;
#pragma unroll
    for (int kb = 0; kb < 4; ++kb) {
      int kk = kb * 256 + tid;
      float e = (kk <= qg) ? __expf(sc[kb][qi] - rmax[qi]) : 0.f;
      sc[kb][qi] = e;
      s += e;
    }
#pragma unroll
    for (int off = 32; off; off >>= 1) s += __shfl_xor(s, off);
    if (lane == 0) redB[qi][wid] = s;
  }
  __syncthreads();
#pragma unroll
  for (int qi = 0; qi < 8; ++qi) {
    float inv = 1.0f / (redB[qi][0] + redB[qi][1] + redB[qi][2] + redB[qi][3]);
    float* Wr = Wout + ((((size_t)bh << 10) + q0 + qi) << 10);
#pragma unroll
    for (int kb = 0; kb < 4; ++kb)
      Wr[kb * 256 + tid] = sc[kb][qi] * inv;
  }
}

// ---------------------------------------------------------------------------
// Kernel 3: PV GEMM per (b,h) (fp32 math, unchanged); epilogue now writes
// ctx directly as bf16 (consumed only by proj MFMA) — saves a cast pass.
// ---------------------------------------------------------------------------
__global__ __launch_bounds__(256) void pv_kernel(
    const float* __restrict__ Wts, const float* __restrict__ V,
    ushort* __restrict__ ctx_bf) {
  __shared__ float Ws[16][64 + 4];
  __shared__ float Vs[16][64];
  int bh = blockIdx.y, bm = blockIdx.x * 64;
  int b = bh >> 4, h = bh & 15;
  const float* Wb = Wts + (((size_t)bh) << 20);
  const float* Vb = V + (((size_t)bh) << 10) * DDIM;
  int tid = threadIdx.x, tx = tid & 15, ty = tid >> 4;
  float acc[4][4] = {};
  for (int k0 = 0; k0 < 1024; k0 += 16) {
    {
      int r = tid >> 2, c = (tid & 3) << 2;
      float4 v = *reinterpret_cast<const float4*>(&Wb[(size_t)(bm + r) * 1024 + k0 + c]);
      Ws[c + 0][r] = v.x; Ws[c + 1][r] = v.y; Ws[c + 2][r] = v.z; Ws[c + 3][r] = v.w;
      int rv = tid >> 4, cv = (tid & 15) << 2;
      *reinterpret_cast<float4*>(&Vs[rv][cv]) =
          *reinterpret_cast<const float4*>(&Vb[(size_t)(k0 + rv) * DDIM + cv]);
    }
    __syncthreads();
#pragma unroll
    for (int kk = 0; kk < 16; ++kk) {
      float4 a = *reinterpret_cast<const float4*>(&Ws[kk][ty << 2]);
      float4 bv = *reinterpret_cast<const float4*>(&Vs[kk][tx << 2]);
      float av[4] = {a.x, a.y, a.z, a.w};
      float bb[4] = {bv.x, bv.y, bv.z, bv.w};
#pragma unroll
      for (int i = 0; i < 4; ++i)
#pragma unroll
        for (int j = 0; j < 4; ++j) acc[i][j] += av[i] * bb[j];
    }
    __syncthreads();
  }
#pragma unroll
  for (int i = 0; i < 4; ++i) {
    int m = bm + (ty << 2) + i;
    ushort4 o;
    o.x = f2bf(acc[i][0]); o.y = f2bf(acc[i][1]);
    o.z = f2bf(acc[i][2]); o.w = f2bf(acc[i][3]);
    *reinterpret_cast<ushort4*>(
        &ctx_bf[(size_t)(b * SDIM + m) * EDIM + h * DDIM + (tx << 2)]) = o;
  }
}

// ---------------------------------------------------------------------------
// Kernel 4 (MFMA): proj GEMM + bias. Clone of validated qkv_gemm_mfma
// structure; epilogue is a plain [m][n] write (no scatter).
// Out[m][n] = sum_k ctx_bf[m][k] * WpT[n][k] + bias[n]
// ---------------------------------------------------------------------------
__global__ __launch_bounds__(256) void proj_gemm_mfma(
    const ushort* __restrict__ Abf, const ushort* __restrict__ WT,
    const float* __restrict__ bias, float* __restrict__ Out) {
  const int K = EDIM;
  __shared__ ushort As[128][40];
  __shared__ ushort Bs[128][40];
  int bm = blockIdx.y * 128, bn = blockIdx.x * 128;
  int tid = threadIdx.x;
  int lane = tid & 63, wave = tid >> 6;
  int wr = (wave >> 1) * 64, wc = (wave & 1) * 64;
  int fr = lane & 15;
  int ko = (lane >> 4) * 8;

  f32x4 acc[4][4] = {};

  for (int k0 = 0; k0 < K; k0 += 32) {
#pragma unroll
    for (int i = 0; i < 2; ++i) {
      int c = tid + i * 256;
      int r = c >> 2, o = (c & 3) * 8;
      *reinterpret_cast<float4*>(&As[r][o]) =
          *reinterpret_cast<const float4*>(&Abf[(size_t)(bm + r) * K + k0 + o]);
      *reinterpret_cast<float4*>(&Bs[r][o]) =
          *reinterpret_cast<const float4*>(&WT[(size_t)(bn + r) * K + k0 + o]);
    }
    __syncthreads();
    bf16x8 a[4], b[4];
#pragma unroll
    for (int f = 0; f < 4; ++f) {
      a[f] = *reinterpret_cast<const bf16x8*>(&As[wr + f * 16 + fr][ko]);
      b[f] = *reinterpret_cast<const bf16x8*>(&Bs[wc + f * 16 + fr][ko]);
    }
#pragma unroll
    for (int i = 0; i < 4; ++i)
#pragma unroll
      for (int j = 0; j < 4; ++j)
        acc[i][j] = __builtin_amdgcn_mfma_f32_16x16x32_bf16(a[i], b[j],
                                                            acc[i][j], 0, 0, 0);
    __syncthreads();
  }

  int rbase = (lane >> 4) << 2;
#pragma unroll
  for (int i = 0; i < 4; ++i)
#pragma unroll
    for (int j = 0; j < 4; ++j)
#pragma unroll
      for (int r = 0; r < 4; ++r) {
        int m = bm + wr + i * 16 + rbase + r;
        int n = bn + wc + j * 16 + (lane & 15);
        Out[(size_t)m * EDIM + n] = acc[i][j][r] + bias[n];
      }
}

extern "C" void kernel_launch(void* const* d_in, const int* in_sizes, int n_in,
                              void* d_out, int out_size, void* d_ws, size_t ws_size,
                              hipStream_t stream) {
  const float* hs     = (const float*)d_in[0];
  const float* W_attn = (const float*)d_in[1];
  const float* b_attn = (const float*)d_in[2];
  const float* W_proj = (const float*)d_in[3];
  const float* b_proj = (const float*)d_in[4];

  float* out_attn = (float*)d_out;                          // [2,1024,1024]
  float* out_w    = (float*)d_out + (size_t)MDIM * EDIM;    // [2,16,1024,1024]

  // ws: Q,K,V fp32 (24 MiB) + ctx_bf (4 MiB) + Abf (4 MiB) + WT (6 MiB)
  //     + WpT (2 MiB) = 40 MiB
  const size_t QSZ = (size_t)BDIM * HDIM * SDIM * DDIM;     // 2 Mi floats
  float* Q   = (float*)d_ws;
  float* Km  = Q + QSZ;
  float* V   = Km + QSZ;
  ushort* ctx_bf = (ushort*)(V + QSZ);
  ushort* Abf = ctx_bf + (size_t)MDIM * EDIM;
  ushort* WT  = Abf + (size_t)MDIM * EDIM;
  ushort* WpT = WT + (size_t)N3 * EDIM;

  cast_bf16_kernel<<<2048, 256, 0, stream>>>(hs, Abf, MDIM * EDIM);
  transpose_cast_kernel<<<dim3(N3 / 32, EDIM / 32), 256, 0, stream>>>(
      W_attn, WT, N3);
  transpose_cast_kernel<<<dim3(EDIM / 32, EDIM / 32), 256, 0, stream>>>(
      W_proj, WpT, EDIM);
  qkv_gemm_mfma<<<dim3(N3 / 128, MDIM / 128), 256, 0, stream>>>(
      Abf, WT, b_attn, Q, Km, V);
  attn_softmax_kernel<<<dim3(SDIM / 8, BDIM * HDIM), 256, 0, stream>>>(
      Q, Km, out_w);
  pv_kernel<<<dim3(SDIM / 64, BDIM * HDIM), 256, 0, stream>>>(
      out_w, V, ctx_bf);
  proj_gemm_mfma<<<dim3(EDIM / 128, MDIM / 128), 256, 0, stream>>>(
      ctx_bf, WpT, b_proj, out_attn);
}

// Round 11
// 338.581 us; speedup vs baseline: 3.7910x; 1.5788x over previous
//
#include <hip/hip_runtime.h>

#define SDIM 1024
#define EDIM 1024
#define BDIM 2
#define HDIM 16
#define DDIM 64
#define MDIM 2048   // B*S
#define N3   3072

typedef __attribute__((ext_vector_type(8))) short bf16x8;
typedef __attribute__((ext_vector_type(4))) float f32x4;

__device__ __forceinline__ ushort f2bf(float f) {
  union { float f; unsigned u; } x; x.f = f;
  unsigned u = x.u;
  u += 0x7FFFu + ((u >> 16) & 1u);   // round-to-nearest-even
  return (ushort)(u >> 16);
}

// ---------------------------------------------------------------------------
// Cast hidden_states fp32 -> bf16 (row-major [2048][1024])
// ---------------------------------------------------------------------------
__global__ __launch_bounds__(256) void cast_bf16_kernel(
    const float* __restrict__ in, ushort* __restrict__ out, int n) {
  int i = (blockIdx.x * 256 + threadIdx.x) * 4;
  if (i < n) {
    float4 v = *reinterpret_cast<const float4*>(&in[i]);
    ushort4 o;
    o.x = f2bf(v.x); o.y = f2bf(v.y); o.z = f2bf(v.z); o.w = f2bf(v.w);
    *reinterpret_cast<ushort4*>(&out[i]) = o;
  }
}

// ---------------------------------------------------------------------------
// Transpose-cast W fp32 [EDIM][ncols] -> WT bf16 [ncols][EDIM]
// ---------------------------------------------------------------------------
__global__ __launch_bounds__(256) void transpose_cast_kernel(
    const float* __restrict__ W, ushort* __restrict__ WT, int ncols) {
  __shared__ float t[32][33];
  int n0 = blockIdx.x * 32, k0 = blockIdx.y * 32;
  int tx = threadIdx.x & 31, ty = threadIdx.x >> 5;   // 32 x 8
#pragma unroll
  for (int j = 0; j < 4; ++j)
    t[ty + j * 8][tx] = W[(size_t)(k0 + ty + j * 8) * ncols + n0 + tx];
  __syncthreads();
#pragma unroll
  for (int j = 0; j < 4; ++j)
    WT[(size_t)(n0 + ty + j * 8) * EDIM + k0 + tx] = f2bf(t[tx][ty + j * 8]);
}

// ---------------------------------------------------------------------------
// Kernel 1 (MFMA): QKV GEMM + bias. Scatter epilogue now writes:
//   Q  fp32 [B,H,S,D]   (softmax LDS q-load, unchanged)
//   KT fp32 [B,H,D,S]   (transposed -> coalesced softmax k-loads)
//   VT bf16 [B,H,D,S]   (transposed bf16 -> pv_mfma B-operand)
// Core loop identical to twice-validated version.
// ---------------------------------------------------------------------------
__global__ __launch_bounds__(256) void qkv_gemm_mfma(
    const ushort* __restrict__ Abf, const ushort* __restrict__ WT,
    const float* __restrict__ bias, float* __restrict__ Qo,
    float* __restrict__ KTo, ushort* __restrict__ VTo) {
  const int K = EDIM;
  __shared__ ushort As[128][40];   // 32 k + 8 pad; row stride 80B
  __shared__ ushort Bs[128][40];
  int bm = blockIdx.y * 128, bn = blockIdx.x * 128;
  int tid = threadIdx.x;
  int lane = tid & 63, wave = tid >> 6;
  int wr = (wave >> 1) * 64, wc = (wave & 1) * 64;
  int fr = lane & 15;
  int ko = (lane >> 4) * 8;

  f32x4 acc[4][4] = {};

  for (int k0 = 0; k0 < K; k0 += 32) {
#pragma unroll
    for (int i = 0; i < 2; ++i) {
      int c = tid + i * 256;
      int r = c >> 2, o = (c & 3) * 8;
      *reinterpret_cast<float4*>(&As[r][o]) =
          *reinterpret_cast<const float4*>(&Abf[(size_t)(bm + r) * K + k0 + o]);
      *reinterpret_cast<float4*>(&Bs[r][o]) =
          *reinterpret_cast<const float4*>(&WT[(size_t)(bn + r) * K + k0 + o]);
    }
    __syncthreads();
    bf16x8 a[4], b[4];
#pragma unroll
    for (int f = 0; f < 4; ++f) {
      a[f] = *reinterpret_cast<const bf16x8*>(&As[wr + f * 16 + fr][ko]);
      b[f] = *reinterpret_cast<const bf16x8*>(&Bs[wc + f * 16 + fr][ko]);
    }
#pragma unroll
    for (int i = 0; i < 4; ++i)
#pragma unroll
      for (int j = 0; j < 4; ++j)
        acc[i][j] = __builtin_amdgcn_mfma_f32_16x16x32_bf16(a[i], b[j],
                                                            acc[i][j], 0, 0, 0);
    __syncthreads();
  }

  int rbase = (lane >> 4) << 2;
#pragma unroll
  for (int i = 0; i < 4; ++i)
#pragma unroll
    for (int j = 0; j < 4; ++j)
#pragma unroll
      for (int r = 0; r < 4; ++r) {
        int m = bm + wr + i * 16 + rbase + r;
        int n = bn + wc + j * 16 + (lane & 15);
        float val = acc[i][j][r] + bias[n];
        int b = m >> 10, s = m & 1023;
        int which = n >> 10;     // 0=q 1=k 2=v
        int e = n & 1023;
        int h = e >> 6, d = e & 63;
        int bh = b * HDIM + h;
        if (which == 0) {
          Qo[(((size_t)bh << 10) + s) * DDIM + d] = val;
        } else if (which == 1) {
          KTo[((size_t)(bh * DDIM + d) << 10) + s] = val;        // transposed
        } else {
          VTo[((size_t)(bh * DDIM + d) << 10) + s] = f2bf(val);  // transposed bf16
        }
      }
}

// ---------------------------------------------------------------------------
// Kernel 2: scores + causal mask + softmax.
// FIX vs R10: thread t owns k-columns 4t..4t+3; K read from KT [B,H,D,S] so
// a wave's float4 loads are CONTIGUOUS (R10 profile: 300us, VALUBusy 24%,
// HBM 7% -> latency-bound on 64-lines-per-load uncoalesced K reads).
// Dynamic d4 loop + 1-deep prefetch (proven R10: no spill, VGPR 64).
// ---------------------------------------------------------------------------
__global__ __launch_bounds__(256) void attn_softmax_kernel(
    const float* __restrict__ Q, const float* __restrict__ KT,
    float* __restrict__ Wout) {
  __shared__ float qs[8][64];
  __shared__ float redA[8][4];
  __shared__ float redB[8][4];
  int bh = blockIdx.y;            // 0..31
  int q0 = blockIdx.x * 8;
  int tid = threadIdx.x;
  int lane = tid & 63, wid = tid >> 6;
  const float* Qb = Q + (((size_t)bh) << 10) * DDIM;
  const float* Kb = KT + ((size_t)bh << 16);   // 64*1024 floats per (b,h)
  if (tid < 128) {
    int r = tid >> 4, c = (tid & 15) << 2;
    *reinterpret_cast<float4*>(&qs[r][c]) =
        *reinterpret_cast<const float4*>(&Qb[(size_t)(q0 + r) * DDIM + c]);
  }
  __syncthreads();

  float sc[4][8];   // sc[j][qi]: score for k = 4*tid+j, q-row q0+qi
#pragma unroll
  for (int j = 0; j < 4; ++j)
#pragma unroll
    for (int qi = 0; qi < 8; ++qi) sc[j][qi] = 0.f;

  const float* kpb = Kb + (tid << 2);          // this thread's k-column base

  // kc_dd = KT[d=4*d4+dd][4t..4t+3]; component j <-> k-col 4t+j
  float4 kc0 = *reinterpret_cast<const float4*>(kpb + (0 << 10));
  float4 kc1 = *reinterpret_cast<const float4*>(kpb + (1 << 10));
  float4 kc2 = *reinterpret_cast<const float4*>(kpb + (2 << 10));
  float4 kc3 = *reinterpret_cast<const float4*>(kpb + (3 << 10));

#pragma unroll 1
  for (int d4 = 0; d4 < 16; ++d4) {
    int nd = (((d4 + 1) & 15) << 2);   // next d base (wraps: harmless re-read)
    float4 kn0 = *reinterpret_cast<const float4*>(kpb + ((size_t)(nd + 0) << 10));
    float4 kn1 = *reinterpret_cast<const float4*>(kpb + ((size_t)(nd + 1) << 10));
    float4 kn2 = *reinterpret_cast<const float4*>(kpb + ((size_t)(nd + 2) << 10));
    float4 kn3 = *reinterpret_cast<const float4*>(kpb + ((size_t)(nd + 3) << 10));
#pragma unroll
    for (int qi = 0; qi < 8; ++qi) {
      float4 q4 = *reinterpret_cast<const float4*>(&qs[qi][d4 << 2]);
      sc[0][qi] += q4.x * kc0.x + q4.y * kc1.x + q4.z * kc2.x + q4.w * kc3.x;
      sc[1][qi] += q4.x * kc0.y + q4.y * kc1.y + q4.z * kc2.y + q4.w * kc3.y;
      sc[2][qi] += q4.x * kc0.z + q4.y * kc1.z + q4.z * kc2.z + q4.w * kc3.z;
      sc[3][qi] += q4.x * kc0.w + q4.y * kc1.w + q4.z * kc2.w + q4.w * kc3.w;
    }
    kc0 = kn0; kc1 = kn1; kc2 = kn2; kc3 = kn3;
  }

  const float scale = 0.125f;   // 1/sqrt(64)
  int kbase = tid << 2;
  float rmax[8];
#pragma unroll
  for (int qi = 0; qi < 8; ++qi) {
    int qg = q0 + qi;
    float m = -3.4e38f;
#pragma unroll
    for (int j = 0; j < 4; ++j) {
      float s = sc[j][qi] * scale;
      sc[j][qi] = s;
      if (kbase + j <= qg) m = fmaxf(m, s);
    }
#pragma unroll
    for (int off = 32; off; off >>= 1) m = fmaxf(m, __shfl_xor(m, off));
    if (lane == 0) redA[qi][wid] = m;
  }
  __syncthreads();
#pragma unroll
  for (int qi = 0; qi < 8; ++qi)
    rmax[qi] = fmaxf(fmaxf(redA[qi][0], redA[qi][1]),
                     fmaxf(redA[qi][2], redA[qi][3]));
#pragma unroll
  for (int qi = 0; qi < 8; ++qi) {
    int qg = q0 + qi;
    float s = 0.f;
#pragma unroll
    for (int j = 0; j < 4; ++j) {
      float e = (kbase + j <= qg) ? __expf(sc[j][qi] - rmax[qi]) : 0.f;
      sc[j][qi] = e;
      s += e;
    }
#pragma unroll
    for (int off = 32; off; off >>= 1) s += __shfl_xor(s, off);
    if (lane == 0) redB[qi][wid] = s;
  }
  __syncthreads();
#pragma unroll
  for (int qi = 0; qi < 8; ++qi) {
    float inv = 1.0f / (redB[qi][0] + redB[qi][1] + redB[qi][2] + redB[qi][3]);
    float* Wr = Wout + ((((size_t)bh << 10) + q0 + qi) << 10);
    float4 w4 = {sc[0][qi] * inv, sc[1][qi] * inv, sc[2][qi] * inv, sc[3][qi] * inv};
    *reinterpret_cast<float4*>(&Wr[kbase]) = w4;   // coalesced
  }
}

// ---------------------------------------------------------------------------
// Kernel 3 (MFMA): PV GEMM per (b,h): ctx[m][d] = sum_k P[m][k] * VT[d][k].
// A = fp32 weights cast to bf16 during LDS staging; B = VT bf16 rows.
// 128(M) x 64(N=D) tile, BK=32; 4 waves 2x2 -> each 64x32 (4x2 frags).
// Writes ctx bf16 for proj MFMA. Replaces fp32 pv_kernel.
// ---------------------------------------------------------------------------
__global__ __launch_bounds__(256) void pv_mfma(
    const float* __restrict__ P, const ushort* __restrict__ VT,
    ushort* __restrict__ ctx_bf) {
  __shared__ ushort As[128][40];
  __shared__ ushort Bs[64][40];
  int bh = blockIdx.y, bm = blockIdx.x * 128;
  int b = bh >> 4, h = bh & 15;
  const float* Pb = P + ((size_t)bh << 20);
  const ushort* Vb = VT + ((size_t)bh << 16);
  int tid = threadIdx.x;
  int lane = tid & 63, wave = tid >> 6;
  int wr = (wave >> 1) * 64, wc = (wave & 1) * 32;
  int fr = lane & 15;
  int ko = (lane >> 4) * 8;

  f32x4 acc[4][2] = {};

  for (int k0 = 0; k0 < SDIM; k0 += 32) {
    // A tile: 128x32 fp32 -> bf16 (4096 elems; 4 float4-chunks per thread)
#pragma unroll
    for (int i = 0; i < 4; ++i) {
      int c = tid + i * 256;            // 0..1023
      int r = c >> 3, o = (c & 7) * 4;  // 8 chunks of 4 elems per row
      float4 v = *reinterpret_cast<const float4*>(&Pb[((size_t)(bm + r) << 10) + k0 + o]);
      ushort4 u;
      u.x = f2bf(v.x); u.y = f2bf(v.y); u.z = f2bf(v.z); u.w = f2bf(v.w);
      *reinterpret_cast<ushort4*>(&As[r][o]) = u;
    }
    // B tile: 64x32 bf16 (256 16B-chunks; 1 per thread)
    {
      int r = tid >> 2, o = (tid & 3) * 8;
      *reinterpret_cast<float4*>(&Bs[r][o]) =
          *reinterpret_cast<const float4*>(&Vb[((size_t)r << 10) + k0 + o]);
    }
    __syncthreads();
    bf16x8 a[4], bb[2];
#pragma unroll
    for (int f = 0; f < 4; ++f)
      a[f] = *reinterpret_cast<const bf16x8*>(&As[wr + f * 16 + fr][ko]);
#pragma unroll
    for (int f = 0; f < 2; ++f)
      bb[f] = *reinterpret_cast<const bf16x8*>(&Bs[wc + f * 16 + fr][ko]);
#pragma unroll
    for (int i = 0; i < 4; ++i)
#pragma unroll
      for (int j = 0; j < 2; ++j)
        acc[i][j] = __builtin_amdgcn_mfma_f32_16x16x32_bf16(a[i], bb[j],
                                                            acc[i][j], 0, 0, 0);
    __syncthreads();
  }

  int rbase = (lane >> 4) << 2;
#pragma unroll
  for (int i = 0; i < 4; ++i)
#pragma unroll
    for (int j = 0; j < 2; ++j)
#pragma unroll
      for (int r = 0; r < 4; ++r) {
        int m = bm + wr + i * 16 + rbase + r;   // s index
        int n = wc + j * 16 + (lane & 15);      // d index
        ctx_bf[(size_t)(b * SDIM + m) * EDIM + h * DDIM + n] = f2bf(acc[i][j][r]);
      }
}

// ---------------------------------------------------------------------------
// Kernel 4 (MFMA): proj GEMM + bias (validated Round 10 — unchanged)
// ---------------------------------------------------------------------------
__global__ __launch_bounds__(256) void proj_gemm_mfma(
    const ushort* __restrict__ Abf, const ushort* __restrict__ WT,
    const float* __restrict__ bias, float* __restrict__ Out) {
  const int K = EDIM;
  __shared__ ushort As[128][40];
  __shared__ ushort Bs[128][40];
  int bm = blockIdx.y * 128, bn = blockIdx.x * 128;
  int tid = threadIdx.x;
  int lane = tid & 63, wave = tid >> 6;
  int wr = (wave >> 1) * 64, wc = (wave & 1) * 64;
  int fr = lane & 15;
  int ko = (lane >> 4) * 8;

  f32x4 acc[4][4] = {};

  for (int k0 = 0; k0 < K; k0 += 32) {
#pragma unroll
    for (int i = 0; i < 2; ++i) {
      int c = tid + i * 256;
      int r = c >> 2, o = (c & 3) * 8;
      *reinterpret_cast<float4*>(&As[r][o]) =
          *reinterpret_cast<const float4*>(&Abf[(size_t)(bm + r) * K + k0 + o]);
      *reinterpret_cast<float4*>(&Bs[r][o]) =
          *reinterpret_cast<const float4*>(&WT[(size_t)(bn + r) * K + k0 + o]);
    }
    __syncthreads();
    bf16x8 a[4], b[4];
#pragma unroll
    for (int f = 0; f < 4; ++f) {
      a[f] = *reinterpret_cast<const bf16x8*>(&As[wr + f * 16 + fr][ko]);
      b[f] = *reinterpret_cast<const bf16x8*>(&Bs[wc + f * 16 + fr][ko]);
    }
#pragma unroll
    for (int i = 0; i < 4; ++i)
#pragma unroll
      for (int j = 0; j < 4; ++j)
        acc[i][j] = __builtin_amdgcn_mfma_f32_16x16x32_bf16(a[i], b[j],
                                                            acc[i][j], 0, 0, 0);
    __syncthreads();
  }

  int rbase = (lane >> 4) << 2;
#pragma unroll
  for (int i = 0; i < 4; ++i)
#pragma unroll
    for (int j = 0; j < 4; ++j)
#pragma unroll
      for (int r = 0; r < 4; ++r) {
        int m = bm + wr + i * 16 + rbase + r;
        int n = bn + wc + j * 16 + (lane & 15);
        Out[(size_t)m * EDIM + n] = acc[i][j][r] + bias[n];
      }
}

extern "C" void kernel_launch(void* const* d_in, const int* in_sizes, int n_in,
                              void* d_out, int out_size, void* d_ws, size_t ws_size,
                              hipStream_t stream) {
  const float* hs     = (const float*)d_in[0];
  const float* W_attn = (const float*)d_in[1];
  const float* b_attn = (const float*)d_in[2];
  const float* W_proj = (const float*)d_in[3];
  const float* b_proj = (const float*)d_in[4];

  float* out_attn = (float*)d_out;                          // [2,1024,1024]
  float* out_w    = (float*)d_out + (size_t)MDIM * EDIM;    // [2,16,1024,1024]

  // ws: Q fp32 8MiB + KT fp32 8MiB + VT bf16 4MiB + ctx_bf 4MiB
  //     + Abf 4MiB + WT 6MiB + WpT 2MiB = 36 MiB
  const size_t QSZ = (size_t)BDIM * HDIM * SDIM * DDIM;     // 2 Mi elems
  float* Q   = (float*)d_ws;
  float* KT  = Q + QSZ;
  ushort* VT = (ushort*)(KT + QSZ);
  ushort* ctx_bf = VT + QSZ;
  ushort* Abf = ctx_bf + (size_t)MDIM * EDIM;
  ushort* WTa = Abf + (size_t)MDIM * EDIM;
  ushort* WpT = WTa + (size_t)N3 * EDIM;

  cast_bf16_kernel<<<2048, 256, 0, stream>>>(hs, Abf, MDIM * EDIM);
  transpose_cast_kernel<<<dim3(N3 / 32, EDIM / 32), 256, 0, stream>>>(
      W_attn, WTa, N3);
  transpose_cast_kernel<<<dim3(EDIM / 32, EDIM / 32), 256, 0, stream>>>(
      W_proj, WpT, EDIM);
  qkv_gemm_mfma<<<dim3(N3 / 128, MDIM / 128), 256, 0, stream>>>(
      Abf, WTa, b_attn, Q, KT, VT);
  attn_softmax_kernel<<<dim3(SDIM / 8, BDIM * HDIM), 256, 0, stream>>>(
      Q, KT, out_w);
  pv_mfma<<<dim3(SDIM / 128, BDIM * HDIM), 256, 0, stream>>>(
      out_w, VT, ctx_bf);
  proj_gemm_mfma<<<dim3(EDIM / 128, MDIM / 128), 256, 0, stream>>>(
      ctx_bf, WpT, b_proj, out_attn);
}

// Round 14
// 275.378 us; speedup vs baseline: 4.6611x; 1.2295x over previous
//
#include <hip/hip_runtime.h>

#define SDIM 1024
#define EDIM 1024
#define BDIM 2
#define HDIM 16
#define DDIM 64
#define MDIM 2048   // B*S
#define N3   3072

typedef __attribute__((ext_vector_type(8))) short bf16x8;
typedef __attribute__((ext_vector_type(4))) float f32x4;

__device__ __forceinline__ ushort f2bf(float f) {
  union { float f; unsigned u; } x; x.f = f;
  unsigned u = x.u;
  u += 0x7FFFu + ((u >> 16) & 1u);   // round-to-nearest-even
  return (ushort)(u >> 16);
}

// ---------------------------------------------------------------------------
// Cast hidden_states fp32 -> bf16 (row-major [2048][1024])
// ---------------------------------------------------------------------------
__global__ __launch_bounds__(256) void cast_bf16_kernel(
    const float* __restrict__ in, ushort* __restrict__ out, int n) {
  int i = (blockIdx.x * 256 + threadIdx.x) * 4;
  if (i < n) {
    float4 v = *reinterpret_cast<const float4*>(&in[i]);
    ushort4 o;
    o.x = f2bf(v.x); o.y = f2bf(v.y); o.z = f2bf(v.z); o.w = f2bf(v.w);
    *reinterpret_cast<ushort4*>(&out[i]) = o;
  }
}

// ---------------------------------------------------------------------------
// Transpose-cast W fp32 [EDIM][ncols] -> WT bf16 [ncols][EDIM]
// ---------------------------------------------------------------------------
__global__ __launch_bounds__(256) void transpose_cast_kernel(
    const float* __restrict__ W, ushort* __restrict__ WT, int ncols) {
  __shared__ float t[32][33];
  int n0 = blockIdx.x * 32, k0 = blockIdx.y * 32;
  int tx = threadIdx.x & 31, ty = threadIdx.x >> 5;   // 32 x 8
#pragma unroll
  for (int j = 0; j < 4; ++j)
    t[ty + j * 8][tx] = W[(size_t)(k0 + ty + j * 8) * ncols + n0 + tx];
  __syncthreads();
#pragma unroll
  for (int j = 0; j < 4; ++j)
    WT[(size_t)(n0 + ty + j * 8) * EDIM + k0 + tx] = f2bf(t[tx][ty + j * 8]);
}

// ---------------------------------------------------------------------------
// Kernel 1 (MFMA): QKV GEMM + bias. Epilogue writes:
//   Qbf bf16 [B,H,S,D], Kbf bf16 [B,H,S,D]  (attn_fused MFMA operands)
//   VT  bf16 [B,H,D,S]                      (pv_mfma B-operand)
// Core loop identical to thrice-validated version.
// ---------------------------------------------------------------------------
__global__ __launch_bounds__(256) void qkv_gemm_mfma(
    const ushort* __restrict__ Abf, const ushort* __restrict__ WT,
    const float* __restrict__ bias, ushort* __restrict__ Qo,
    ushort* __restrict__ Ko, ushort* __restrict__ VTo) {
  const int K = EDIM;
  __shared__ ushort As[128][40];   // 32 k + 8 pad; row stride 80B
  __shared__ ushort Bs[128][40];
  int bm = blockIdx.y * 128, bn = blockIdx.x * 128;
  int tid = threadIdx.x;
  int lane = tid & 63, wave = tid >> 6;
  int wr = (wave >> 1) * 64, wc = (wave & 1) * 64;
  int fr = lane & 15;
  int ko = (lane >> 4) * 8;

  f32x4 acc[4][4] = {};

  for (int k0 = 0; k0 < K; k0 += 32) {
#pragma unroll
    for (int i = 0; i < 2; ++i) {
      int c = tid + i * 256;
      int r = c >> 2, o = (c & 3) * 8;
      *reinterpret_cast<float4*>(&As[r][o]) =
          *reinterpret_cast<const float4*>(&Abf[(size_t)(bm + r) * K + k0 + o]);
      *reinterpret_cast<float4*>(&Bs[r][o]) =
          *reinterpret_cast<const float4*>(&WT[(size_t)(bn + r) * K + k0 + o]);
    }
    __syncthreads();
    bf16x8 a[4], b[4];
#pragma unroll
    for (int f = 0; f < 4; ++f) {
      a[f] = *reinterpret_cast<const bf16x8*>(&As[wr + f * 16 + fr][ko]);
      b[f] = *reinterpret_cast<const bf16x8*>(&Bs[wc + f * 16 + fr][ko]);
    }
#pragma unroll
    for (int i = 0; i < 4; ++i)
#pragma unroll
      for (int j = 0; j < 4; ++j)
        acc[i][j] = __builtin_amdgcn_mfma_f32_16x16x32_bf16(a[i], b[j],
                                                            acc[i][j], 0, 0, 0);
    __syncthreads();
  }

  int rbase = (lane >> 4) << 2;
#pragma unroll
  for (int i = 0; i < 4; ++i)
#pragma unroll
    for (int j = 0; j < 4; ++j)
#pragma unroll
      for (int r = 0; r < 4; ++r) {
        int m = bm + wr + i * 16 + rbase + r;
        int n = bn + wc + j * 16 + (lane & 15);
        float val = acc[i][j][r] + bias[n];
        int b = m >> 10, s = m & 1023;
        int which = n >> 10;     // 0=q 1=k 2=v
        int e = n & 1023;
        int h = e >> 6, d = e & 63;
        int bh = b * HDIM + h;
        if (which == 0) {
          Qo[(((size_t)bh << 10) + s) * DDIM + d] = f2bf(val);
        } else if (which == 1) {
          Ko[(((size_t)bh << 10) + s) * DDIM + d] = f2bf(val);
        } else {
          VTo[((size_t)(bh * DDIM + d) << 10) + s] = f2bf(val);  // transposed
        }
      }
}

// ---------------------------------------------------------------------------
// Kernel 2 (MFMA, fused): scores + causal mask + softmax, writes weights once.
// Block = (b,h) x 64 q-rows; wave w owns q-rows qw..qw+15. K panel staged
// tile-wise (128x64 bf16 = 18KB LDS, [128][72] pad -> 2-way banks, free).
// Two-pass online softmax (no score storage): pass A tracks (m,l) per row
// via 16-lane shfl reduce; pass B recomputes scores, writes exp(s-m)/l.
// Causal: tiles beyond (q0>>7) skipped; masked region written as exact 0
// (matches fp32 exp(-10000-m) underflow). C-layout: col(k)=lane&15,
// row(q)=(lane>>4)*4+reg (thrice-validated mapping).
// ---------------------------------------------------------------------------
__global__ __launch_bounds__(256) void attn_fused_kernel(
    const ushort* __restrict__ Qbf, const ushort* __restrict__ Kbf,
    float* __restrict__ Wout) {
  __shared__ ushort Ks[128][72];   // 64 d + 8 pad; row 144B (16B-aligned)
  int bh = blockIdx.y;
  int q0 = blockIdx.x * 64;
  int tid = threadIdx.x;
  int lane = tid & 63, wave = tid >> 6;
  int qw = q0 + wave * 16;
  const ushort* Qb = Qbf + (((size_t)bh) << 10) * DDIM;
  const ushort* Kb = Kbf + (((size_t)bh) << 10) * DDIM;

  // per-wave Q fragments (held for whole kernel)
  bf16x8 aq[2];
  {
    int qrow = qw + (lane & 15);
#pragma unroll
    for (int ds = 0; ds < 2; ++ds)
      aq[ds] = *reinterpret_cast<const bf16x8*>(
          &Qb[(size_t)qrow * DDIM + ds * 32 + ((lane >> 4) << 3)]);
  }

  const float scale = 0.125f;      // 1/sqrt(64)
  int rq = (lane >> 4) << 2;       // q-row base of this lane group
  float m[4], l[4];
#pragma unroll
  for (int r = 0; r < 4; ++r) { m[r] = -3.4e38f; l[r] = 0.f; }

  int ntA = (q0 >> 7) + 1;         // causal tile count (block-uniform)

  // ---------------- pass A: online (m,l) ----------------
  for (int kt = 0; kt < ntA; ++kt) {
    __syncthreads();
#pragma unroll
    for (int i = 0; i < 4; ++i) {
      int c = tid + i * 256;       // 16B-chunk id, 1024 per tile
      int r = c >> 3, o = (c & 7) * 8;
      *reinterpret_cast<float4*>(&Ks[r][o]) =
          *reinterpret_cast<const float4*>(&Kb[(size_t)(kt * 128 + r) * DDIM + o]);
    }
    __syncthreads();
    f32x4 acc[8];
#pragma unroll
    for (int nf = 0; nf < 8; ++nf) {
      bf16x8 b0 = *reinterpret_cast<const bf16x8*>(
          &Ks[nf * 16 + (lane & 15)][(lane >> 4) << 3]);
      bf16x8 b1 = *reinterpret_cast<const bf16x8*>(
          &Ks[nf * 16 + (lane & 15)][32 + ((lane >> 4) << 3)]);
      f32x4 z = {0.f, 0.f, 0.f, 0.f};
      z = __builtin_amdgcn_mfma_f32_16x16x32_bf16(aq[0], b0, z, 0, 0, 0);
      z = __builtin_amdgcn_mfma_f32_16x16x32_bf16(aq[1], b1, z, 0, 0, 0);
      acc[nf] = z;
    }
    int kc = kt * 128 + (lane & 15);
#pragma unroll
    for (int r = 0; r < 4; ++r) {
      int q = qw + rq + r;
      float sv[8], tmax = -3.4e38f;
#pragma unroll
      for (int nf = 0; nf < 8; ++nf) {
        float s = acc[nf][r] * scale;
        sv[nf] = (kc + nf * 16 <= q) ? s : -3.4e38f;
        tmax = fmaxf(tmax, sv[nf]);
      }
#pragma unroll
      for (int off = 8; off; off >>= 1) tmax = fmaxf(tmax, __shfl_xor(tmax, off));
      float mn = fmaxf(m[r], tmax);
      float ps = 0.f;
#pragma unroll
      for (int nf = 0; nf < 8; ++nf) ps += __expf(sv[nf] - mn);
#pragma unroll
      for (int off = 8; off; off >>= 1) ps += __shfl_xor(ps, off);
      l[r] = l[r] * __expf(m[r] - mn) + ps;
      m[r] = mn;
    }
  }

  float linv[4];
#pragma unroll
  for (int r = 0; r < 4; ++r) linv[r] = 1.0f / l[r];

  float* Wr = Wout + ((size_t)bh << 20);

  // ---------------- pass B: recompute + write ----------------
  for (int kt = 0; kt < ntA; ++kt) {
    __syncthreads();
#pragma unroll
    for (int i = 0; i < 4; ++i) {
      int c = tid + i * 256;
      int r = c >> 3, o = (c & 7) * 8;
      *reinterpret_cast<float4*>(&Ks[r][o]) =
          *reinterpret_cast<const float4*>(&Kb[(size_t)(kt * 128 + r) * DDIM + o]);
    }
    __syncthreads();
    f32x4 acc[8];
#pragma unroll
    for (int nf = 0; nf < 8; ++nf) {
      bf16x8 b0 = *reinterpret_cast<const bf16x8*>(
          &Ks[nf * 16 + (lane & 15)][(lane >> 4) << 3]);
      bf16x8 b1 = *reinterpret_cast<const bf16x8*>(
          &Ks[nf * 16 + (lane & 15)][32 + ((lane >> 4) << 3)]);
      f32x4 z = {0.f, 0.f, 0.f, 0.f};
      z = __builtin_amdgcn_mfma_f32_16x16x32_bf16(aq[0], b0, z, 0, 0, 0);
      z = __builtin_amdgcn_mfma_f32_16x16x32_bf16(aq[1], b1, z, 0, 0, 0);
      acc[nf] = z;
    }
    int kc = kt * 128 + (lane & 15);
#pragma unroll
    for (int nf = 0; nf < 8; ++nf) {
      int k = kc + nf * 16;
#pragma unroll
      for (int r = 0; r < 4; ++r) {
        int q = qw + rq + r;
        float w = (k <= q) ? __expf(acc[nf][r] * scale - m[r]) * linv[r] : 0.f;
        Wr[((size_t)q << 10) + k] = w;
      }
    }
  }
  // masked tiles: exact zeros (no K staging needed)
  for (int kt = ntA; kt < 8; ++kt) {
    int kc = kt * 128 + (lane & 15);
#pragma unroll
    for (int nf = 0; nf < 8; ++nf)
#pragma unroll
      for (int r = 0; r < 4; ++r)
        Wr[((size_t)(qw + rq + r) << 10) + kc + nf * 16] = 0.f;
  }
}

// ---------------------------------------------------------------------------
// Kernel 3 (MFMA): PV GEMM per (b,h) (validated Round 11 — unchanged)
// ---------------------------------------------------------------------------
__global__ __launch_bounds__(256) void pv_mfma(
    const float* __restrict__ P, const ushort* __restrict__ VT,
    ushort* __restrict__ ctx_bf) {
  __shared__ ushort As[128][40];
  __shared__ ushort Bs[64][40];
  int bh = blockIdx.y, bm = blockIdx.x * 128;
  int b = bh >> 4, h = bh & 15;
  const float* Pb = P + ((size_t)bh << 20);
  const ushort* Vb = VT + ((size_t)bh << 16);
  int tid = threadIdx.x;
  int lane = tid & 63, wave = tid >> 6;
  int wr = (wave >> 1) * 64, wc = (wave & 1) * 32;
  int fr = lane & 15;
  int ko = (lane >> 4) * 8;

  f32x4 acc[4][2] = {};

  for (int k0 = 0; k0 < SDIM; k0 += 32) {
#pragma unroll
    for (int i = 0; i < 4; ++i) {
      int c = tid + i * 256;
      int r = c >> 3, o = (c & 7) * 4;
      float4 v = *reinterpret_cast<const float4*>(&Pb[((size_t)(bm + r) << 10) + k0 + o]);
      ushort4 u;
      u.x = f2bf(v.x); u.y = f2bf(v.y); u.z = f2bf(v.z); u.w = f2bf(v.w);
      *reinterpret_cast<ushort4*>(&As[r][o]) = u;
    }
    {
      int r = tid >> 2, o = (tid & 3) * 8;
      *reinterpret_cast<float4*>(&Bs[r][o]) =
          *reinterpret_cast<const float4*>(&Vb[((size_t)r << 10) + k0 + o]);
    }
    __syncthreads();
    bf16x8 a[4], bb[2];
#pragma unroll
    for (int f = 0; f < 4; ++f)
      a[f] = *reinterpret_cast<const bf16x8*>(&As[wr + f * 16 + fr][ko]);
#pragma unroll
    for (int f = 0; f < 2; ++f)
      bb[f] = *reinterpret_cast<const bf16x8*>(&Bs[wc + f * 16 + fr][ko]);
#pragma unroll
    for (int i = 0; i < 4; ++i)
#pragma unroll
      for (int j = 0; j < 2; ++j)
        acc[i][j] = __builtin_amdgcn_mfma_f32_16x16x32_bf16(a[i], bb[j],
                                                            acc[i][j], 0, 0, 0);
    __syncthreads();
  }

  int rbase = (lane >> 4) << 2;
#pragma unroll
  for (int i = 0; i < 4; ++i)
#pragma unroll
    for (int j = 0; j < 2; ++j)
#pragma unroll
      for (int r = 0; r < 4; ++r) {
        int m = bm + wr + i * 16 + rbase + r;
        int n = wc + j * 16 + (lane & 15);
        ctx_bf[(size_t)(b * SDIM + m) * EDIM + h * DDIM + n] = f2bf(acc[i][j][r]);
      }
}

// ---------------------------------------------------------------------------
// Kernel 4 (MFMA): proj GEMM + bias (validated Round 10/11 — unchanged)
// ---------------------------------------------------------------------------
__global__ __launch_bounds__(256) void proj_gemm_mfma(
    const ushort* __restrict__ Abf, const ushort* __restrict__ WT,
    const float* __restrict__ bias, float* __restrict__ Out) {
  const int K = EDIM;
  __shared__ ushort As[128][40];
  __shared__ ushort Bs[128][40];
  int bm = blockIdx.y * 128, bn = blockIdx.x * 128;
  int tid = threadIdx.x;
  int lane = tid & 63, wave = tid >> 6;
  int wr = (wave >> 1) * 64, wc = (wave & 1) * 64;
  int fr = lane & 15;
  int ko = (lane >> 4) * 8;

  f32x4 acc[4][4] = {};

  for (int k0 = 0; k0 < K; k0 += 32) {
#pragma unroll
    for (int i = 0; i < 2; ++i) {
      int c = tid + i * 256;
      int r = c >> 2, o = (c & 3) * 8;
      *reinterpret_cast<float4*>(&As[r][o]) =
          *reinterpret_cast<const float4*>(&Abf[(size_t)(bm + r) * K + k0 + o]);
      *reinterpret_cast<float4*>(&Bs[r][o]) =
          *reinterpret_cast<const float4*>(&WT[(size_t)(bn + r) * K + k0 + o]);
    }
    __syncthreads();
    bf16x8 a[4], b[4];
#pragma unroll
    for (int f = 0; f < 4; ++f) {
      a[f] = *reinterpret_cast<const bf16x8*>(&As[wr + f * 16 + fr][ko]);
      b[f] = *reinterpret_cast<const bf16x8*>(&Bs[wc + f * 16 + fr][ko]);
    }
#pragma unroll
    for (int i = 0; i < 4; ++i)
#pragma unroll
      for (int j = 0; j < 4; ++j)
        acc[i][j] = __builtin_amdgcn_mfma_f32_16x16x32_bf16(a[i], b[j],
                                                            acc[i][j], 0, 0, 0);
    __syncthreads();
  }

  int rbase = (lane >> 4) << 2;
#pragma unroll
  for (int i = 0; i < 4; ++i)
#pragma unroll
    for (int j = 0; j < 4; ++j)
#pragma unroll
      for (int r = 0; r < 4; ++r) {
        int m = bm + wr + i * 16 + rbase + r;
        int n = bn + wc + j * 16 + (lane & 15);
        Out[(size_t)m * EDIM + n] = acc[i][j][r] + bias[n];
      }
}

extern "C" void kernel_launch(void* const* d_in, const int* in_sizes, int n_in,
                              void* d_out, int out_size, void* d_ws, size_t ws_size,
                              hipStream_t stream) {
  const float* hs     = (const float*)d_in[0];
  const float* W_attn = (const float*)d_in[1];
  const float* b_attn = (const float*)d_in[2];
  const float* W_proj = (const float*)d_in[3];
  const float* b_proj = (const float*)d_in[4];

  float* out_attn = (float*)d_out;                          // [2,1024,1024]
  float* out_w    = (float*)d_out + (size_t)MDIM * EDIM;    // [2,16,1024,1024]

  // ws: Qbf 4MiB + Kbf 4MiB + VT 4MiB + ctx_bf 4MiB + Abf 4MiB
  //     + WTa 6MiB + WpT 2MiB = 28 MiB
  const size_t QSZ = (size_t)BDIM * HDIM * SDIM * DDIM;     // 2 Mi elems
  ushort* Qbf = (ushort*)d_ws;
  ushort* Kbf = Qbf + QSZ;
  ushort* VT  = Kbf + QSZ;
  ushort* ctx_bf = VT + QSZ;
  ushort* Abf = ctx_bf + (size_t)MDIM * EDIM;
  ushort* WTa = Abf + (size_t)MDIM * EDIM;
  ushort* WpT = WTa + (size_t)N3 * EDIM;

  cast_bf16_kernel<<<2048, 256, 0, stream>>>(hs, Abf, MDIM * EDIM);
  transpose_cast_kernel<<<dim3(N3 / 32, EDIM / 32), 256, 0, stream>>>(
      W_attn, WTa, N3);
  transpose_cast_kernel<<<dim3(EDIM / 32, EDIM / 32), 256, 0, stream>>>(
      W_proj, WpT, EDIM);
  qkv_gemm_mfma<<<dim3(N3 / 128, MDIM / 128), 256, 0, stream>>>(
      Abf, WTa, b_attn, Qbf, Kbf, VT);
  attn_fused_kernel<<<dim3(SDIM / 64, BDIM * HDIM), 256, 0, stream>>>(
      Qbf, Kbf, out_w);
  pv_mfma<<<dim3(SDIM / 128, BDIM * HDIM), 256, 0, stream>>>(
      out_w, VT, ctx_bf);
  proj_gemm_mfma<<<dim3(EDIM / 128, MDIM / 128), 256, 0, stream>>>(
      ctx_bf, WpT, b_proj, out_attn);
}